// Round 6
// baseline (36.472 us; speedup 1.0000x reference)
//
#include <hip/hip_runtime.h>
#include <stdint.h>

typedef unsigned long long u64;
typedef __attribute__((ext_vector_type(8))) short bf16x8;   // 8 bf16 (4 VGPRs)
typedef __attribute__((ext_vector_type(4))) float f32x4;    // MFMA acc

#define IN_FEATURES 256
#define UNITS 256
#define BM 32          // rows per tile
#define LDK 264        // padded LDS row stride in ushorts (528 B)

// sign(x) as bf16 bits: 0 for ±0, else ±1.0 (0x3F80 | signbit). Exact.
__device__ __forceinline__ ushort sgn_bf16(float f) {
    uint u = __float_as_uint(f);
    return ((u << 1) == 0u) ? (ushort)0 : (ushort)(0x3F80u | ((u >> 16) & 0x8000u));
}
__device__ __forceinline__ uint sgn_pack2(float a, float b) {
    return (uint)sgn_bf16(a) | ((uint)sgn_bf16(b) << 16);
}

// ---------------------------------------------------------------------------
// Pack kernel: w -> sign-bf16 in MFMA fragment layout (zero-divergence B loads).
// Fragment f=(ks,ct,lane): col = ct*16 + (lane&15), k = ks*32 + (lane>>4)*8 .. +8
// fragB element index: ((ks*16 + ct)*64 + lane) * 8 ushorts.  Total 128 KB.
// ---------------------------------------------------------------------------
__global__ __launch_bounds__(256) void pack_w_frag(const float* __restrict__ w,
                                                   ushort* __restrict__ fragB) {
    __shared__ ushort ls[256][17];  // [k][c], +1 pad
    const int ct = blockIdx.x;      // col-tile 0..15
    const int t = threadIdx.x;

    const float4* wr = (const float4*)(w + (size_t)t * UNITS + ct * 16);
#pragma unroll
    for (int i = 0; i < 4; ++i) {
        const float4 v = wr[i];
        ls[t][i * 4 + 0] = sgn_bf16(v.x);
        ls[t][i * 4 + 1] = sgn_bf16(v.y);
        ls[t][i * 4 + 2] = sgn_bf16(v.z);
        ls[t][i * 4 + 3] = sgn_bf16(v.w);
    }
    __syncthreads();

#pragma unroll
    for (int h = 0; h < 2; ++h) {
        const int f = t + h * 256;
        const int ks = f >> 6;        // 0..7
        const int lane = f & 63;
        const int c = lane & 15;
        const int k0 = ks * 32 + (lane >> 4) * 8;
        alignas(16) ushort tmp[8];
#pragma unroll
        for (int j = 0; j < 8; ++j) tmp[j] = ls[k0 + j][c];
        *(uint4*)(fragB + ((size_t)(ks * 16 + ct) * 64 + lane) * 8) = *(const uint4*)tmp;
    }
}

// ---------------------------------------------------------------------------
// Compute one 32-row tile from LDS + store it.
// SWAPPED MFMA operands: mfma(b, a, acc) computes the transposed C tile, so
// lane holds C[row = lane&15][4 consecutive cols at (lane>>4)*4] -> dwordx4
// stores. (A/B operand lane maps are identical for 16x16x32, both verified
// absmax-0 in round 5, so the swap is exact.)
// ---------------------------------------------------------------------------
__device__ __forceinline__ void compute_store_tile(const ushort (*xs)[LDK],
                                                   const ushort* __restrict__ fragB,
                                                   float* __restrict__ out,
                                                   long rowT, int lane, int wid) {
    const int rl = lane & 15;
    const int klb = (lane >> 4) * 8;
    const int cl4 = (lane >> 4) * 4;
    const int ct0 = wid * 4;
    const int colbase = wid * 64;

    f32x4 acc[2][4];
#pragma unroll
    for (int mt = 0; mt < 2; ++mt)
#pragma unroll
        for (int nt = 0; nt < 4; ++nt) acc[mt][nt] = (f32x4){0.f, 0.f, 0.f, 0.f};

#pragma unroll
    for (int ks = 0; ks < 8; ++ks) {
        const int kk = ks * 32 + klb;
        bf16x8 a[2], b[4];
        a[0] = *(const bf16x8*)&xs[rl][kk];          // ds_read_b128
        a[1] = *(const bf16x8*)&xs[16 + rl][kk];
        const ushort* bp = fragB + ((size_t)(ks * 16 + ct0) * 64 + lane) * 8;
#pragma unroll
        for (int nt = 0; nt < 4; ++nt)
            b[nt] = *(const bf16x8*)(bp + nt * 512);  // coalesced 1KB/wave, L2

#pragma unroll
        for (int mt = 0; mt < 2; ++mt)
#pragma unroll
            for (int nt = 0; nt < 4; ++nt)
                acc[mt][nt] = __builtin_amdgcn_mfma_f32_16x16x32_bf16(
                    b[nt], a[mt], acc[mt][nt], 0, 0, 0);
    }

    // store: lane -> C[rowT + mt*16 + rl][colbase + nt*16 + cl4 .. +4]
#pragma unroll
    for (int mt = 0; mt < 2; ++mt)
#pragma unroll
        for (int nt = 0; nt < 4; ++nt)
            *(f32x4*)(out + (rowT + mt * 16 + rl) * UNITS + colbase + nt * 16 + cl4) =
                acc[mt][nt];
}

// ---------------------------------------------------------------------------
// Main kernel: 2 tiles of 32 rows per block, software-pipelined.
// Tile-1 global loads are issued BEFORE tile-0 compute (T14 async-STAGE),
// so tile-1's read stream hides under tile-0's compute + store.
// Staging map: wave w stages rows {w, 4+w, ..., 28+w}, lane = float4 col.
// ---------------------------------------------------------------------------
__global__ __launch_bounds__(256, 4) void bdense_mfma4(const float4* __restrict__ x4,
                                                       const ushort* __restrict__ fragB,
                                                       float* __restrict__ out) {
    __shared__ ushort xs[BM][LDK];  // 16896 B

    const int tid = threadIdx.x;
    const int lane = tid & 63;
    const int wid = tid >> 6;
    const long rowblk = (long)blockIdx.x * (2 * BM);

    float4 v[8];

    // ---- load tile 0 (coalesced float4) ----
#pragma unroll
    for (int i = 0; i < 8; ++i)
        v[i] = x4[(rowblk + i * 4 + wid) * (IN_FEATURES / 4) + lane];

    // ---- LDS write tile 0 (sign -> bf16) ----
#pragma unroll
    for (int i = 0; i < 8; ++i)
        *(uint2*)&xs[i * 4 + wid][lane * 4] =
            make_uint2(sgn_pack2(v[i].x, v[i].y), sgn_pack2(v[i].z, v[i].w));
    __syncthreads();

    // ---- issue tile-1 loads (in flight across tile-0 compute/store) ----
#pragma unroll
    for (int i = 0; i < 8; ++i)
        v[i] = x4[(rowblk + BM + i * 4 + wid) * (IN_FEATURES / 4) + lane];

    // ---- compute + store tile 0 ----
    compute_store_tile(xs, fragB, out, rowblk, lane, wid);

    __syncthreads();  // all waves done reading xs before overwrite

    // ---- LDS write tile 1 ----
#pragma unroll
    for (int i = 0; i < 8; ++i)
        *(uint2*)&xs[i * 4 + wid][lane * 4] =
            make_uint2(sgn_pack2(v[i].x, v[i].y), sgn_pack2(v[i].z, v[i].w));
    __syncthreads();

    // ---- compute + store tile 1 ----
    compute_store_tile(xs, fragB, out, rowblk + BM, lane, wid);
}

// ---------------------------------------------------------------------------
// Fallback (ws too small): round-2 popcount path, known-correct.
// ---------------------------------------------------------------------------
__global__ __launch_bounds__(256) void pack_w_bits(const float* __restrict__ w,
                                                   u64* __restrict__ wp) {
    const int t = blockIdx.x;
    const int j = threadIdx.x;
    u64 s = 0, z = 0;
#pragma unroll
    for (int b = 0; b < 64; ++b) {
        const float v = w[(4 * b + t) * UNITS + j];
        s |= ((u64)(v < 0.0f)) << b;
        z |= ((u64)(v != 0.0f)) << b;
    }
    wp[j * 4 + t] = s;
    wp[1024 + j * 4 + t] = z;
}

__global__ __launch_bounds__(256) void bdense_pop(const float4* __restrict__ x4,
                                                  const u64* __restrict__ wp,
                                                  float4* __restrict__ out4) {
    const int tid = threadIdx.x;
    const int lane = tid & 63;
    const int wid = tid >> 6;
    const long row0 = (long)blockIdx.x * 32 + (long)wid * 8;

    u64 ws_[4][4], wz_[4][4];
#pragma unroll
    for (int i = 0; i < 4; ++i)
#pragma unroll
        for (int t = 0; t < 4; ++t) {
            ws_[i][t] = wp[(4 * lane + i) * 4 + t];
            wz_[i][t] = wp[1024 + (4 * lane + i) * 4 + t];
        }

#pragma unroll
    for (int r = 0; r < 8; ++r) {
        const float4 v = x4[(row0 + r) * (IN_FEATURES / 4) + lane];
        u64 rs[4], rz[4];
        rs[0] = __ballot(v.x < 0.0f); rz[0] = __ballot(v.x != 0.0f);
        rs[1] = __ballot(v.y < 0.0f); rz[1] = __ballot(v.y != 0.0f);
        rs[2] = __ballot(v.z < 0.0f); rz[2] = __ballot(v.z != 0.0f);
        rs[3] = __ballot(v.w < 0.0f); rz[3] = __ballot(v.w != 0.0f);
        float o[4];
#pragma unroll
        for (int i = 0; i < 4; ++i) {
            int nzc = 0, ngc = 0;
#pragma unroll
            for (int t = 0; t < 4; ++t) {
                const u64 nz = rz[t] & wz_[i][t];
                const u64 d = (rs[t] ^ ws_[i][t]) & nz;
                nzc += __popcll(nz);
                ngc += __popcll(d);
            }
            o[i] = (float)(nzc - 2 * ngc);
        }
        out4[(row0 + r) * (UNITS / 4) + lane] = make_float4(o[0], o[1], o[2], o[3]);
    }
}

extern "C" void kernel_launch(void* const* d_in, const int* in_sizes, int n_in,
                              void* d_out, int out_size, void* d_ws, size_t ws_size,
                              hipStream_t stream) {
    const float* x = (const float*)d_in[0];
    const float* w = (const float*)d_in[1];
    float* out = (float*)d_out;

    const int batch = in_sizes[0] / IN_FEATURES;  // 65536

    if (ws_size >= (size_t)UNITS * IN_FEATURES * sizeof(ushort)) {  // 128 KB
        ushort* fragB = (ushort*)d_ws;
        pack_w_frag<<<16, 256, 0, stream>>>(w, fragB);
        bdense_mfma4<<<batch / (2 * BM), 256, 0, stream>>>((const float4*)x, fragB, out);
    } else {
        u64* wp = (u64*)d_ws;  // 16 KB
        pack_w_bits<<<4, 256, 0, stream>>>(w, wp);
        bdense_pop<<<batch / 32, 256, 0, stream>>>((const float4*)x, wp, (float4*)out);
    }
}

// Round 7
// 35.254 us; speedup vs baseline: 1.0346x; 1.0346x over previous
//
#include <hip/hip_runtime.h>
#include <stdint.h>

typedef unsigned long long u64;
typedef __attribute__((ext_vector_type(4))) float f32x4;    // MFMA acc

#define IN_FEATURES 256
#define UNITS 256
#define BM 32          // rows per block
#define LDP 272        // LDS row pitch in BYTES (256 + 16; 8-aligned, 4-bank rotation)

// ---- sign helpers ----
// fp8 e4m3fn: +1.0 = 0x38, -1.0 = 0xB8, 0 = 0x00. Exact for {-1,0,1}.
__device__ __forceinline__ uint sgn_fp8(float f) {
    uint u = __float_as_uint(f);
    return ((u << 1) == 0u) ? 0u : (0x38u | ((u >> 24) & 0x80u));
}
__device__ __forceinline__ uint sgn_fp8_pack4(float4 v) {
    return sgn_fp8(v.x) | (sgn_fp8(v.y) << 8) | (sgn_fp8(v.z) << 16) | (sgn_fp8(v.w) << 24);
}

// ---------------------------------------------------------------------------
// Pack kernel: w -> sign-fp8 in MFMA B-fragment layout (zero-divergence loads).
// Fragment (ks, ct, lane): col = ct*16 + (lane&15), k = ks*32 + (lane>>4)*8 .. +8
// fragB[u64 index (ks*16+ct)*64 + lane] = 8 fp8 bytes, k-ascending.  Total 64 KB.
// A-fragments are packed with the *identical* (lane,byte)->k map, so any HW
// internal k-permutation cancels between A and B.
// ---------------------------------------------------------------------------
__global__ __launch_bounds__(256) void pack_w_frag8(const float* __restrict__ w,
                                                    u64* __restrict__ fragB) {
    __shared__ uchar ls[256][20];   // [k][c], padded
    const int ct = blockIdx.x;      // col-tile 0..15
    const int t = threadIdx.x;

    const float4* wr = (const float4*)(w + (size_t)t * UNITS + ct * 16);
#pragma unroll
    for (int i = 0; i < 4; ++i) {
        const float4 v = wr[i];
        ls[t][i * 4 + 0] = (uchar)sgn_fp8(v.x);
        ls[t][i * 4 + 1] = (uchar)sgn_fp8(v.y);
        ls[t][i * 4 + 2] = (uchar)sgn_fp8(v.z);
        ls[t][i * 4 + 3] = (uchar)sgn_fp8(v.w);
    }
    __syncthreads();

#pragma unroll
    for (int h = 0; h < 2; ++h) {
        const int f = t + h * 256;
        const int ks = f >> 6;          // 0..7
        const int lane = f & 63;
        const int c = lane & 15;
        const int k0 = ks * 32 + (lane >> 4) * 8;
        u64 val = 0;
#pragma unroll
        for (int j = 0; j < 8; ++j) val |= ((u64)ls[k0 + j][c]) << (8 * j);
        fragB[(size_t)(ks * 16 + ct) * 64 + lane] = val;
    }
}

// ---------------------------------------------------------------------------
// Main kernel: fp8 MFMA, BM=32 rows/block, 4 waves x 64 cols each.
// Stage is BATCHED (8 loads in flight before any conversion) -> ~128 KB/CU
// of reads outstanding during staging. fp8 halves LDS + fragB traffic.
// Swapped-operand MFMA (verified absmax-0 in round 6) -> dwordx4 C stores.
// Grid 2048, LDS 8.7 KB, target VGPR <= 85 -> ~8 blocks/CU resident.
// ---------------------------------------------------------------------------
__global__ __launch_bounds__(256, 6) void bdense_fp8(const float4* __restrict__ x4,
                                                     const u64* __restrict__ fragB,
                                                     float* __restrict__ out) {
    __shared__ uchar xs[BM][LDP];   // 8704 B

    const int tid = threadIdx.x;
    const int lane = tid & 63;
    const int wid = tid >> 6;
    const long row0 = (long)blockIdx.x * BM;

    // ---- batched stage: wave w loads rows {w,4+w,...,28+w}, lane = float4 col ----
    float4 v[8];
#pragma unroll
    for (int j = 0; j < 8; ++j)
        v[j] = x4[(row0 + j * 4 + wid) * (IN_FEATURES / 4) + lane];
#pragma unroll
    for (int j = 0; j < 8; ++j)
        *(uint*)&xs[j * 4 + wid][lane * 4] = sgn_fp8_pack4(v[j]);
    __syncthreads();

    const int rl = lane & 15;
    const int kg8 = (lane >> 4) * 8;
    const int ct0 = wid * 4;

    f32x4 acc[2][4];
#pragma unroll
    for (int mt = 0; mt < 2; ++mt)
#pragma unroll
        for (int nt = 0; nt < 4; ++nt) acc[mt][nt] = (f32x4){0.f, 0.f, 0.f, 0.f};

#pragma unroll
    for (int ks = 0; ks < 8; ++ks) {
        const int ko = ks * 32 + kg8;
        const long a0 = *(const long*)&xs[rl][ko];         // ds_read_b64
        const long a1 = *(const long*)&xs[16 + rl][ko];
        long b[4];
#pragma unroll
        for (int nt = 0; nt < 4; ++nt)                      // coalesced 512B/wave, L2
            b[nt] = ((const long*)fragB)[(size_t)(ks * 16 + ct0 + nt) * 64 + lane];
#pragma unroll
        for (int nt = 0; nt < 4; ++nt) {
            acc[0][nt] = __builtin_amdgcn_mfma_f32_16x16x32_fp8_fp8(b[nt], a0, acc[0][nt], 0, 0, 0);
            acc[1][nt] = __builtin_amdgcn_mfma_f32_16x16x32_fp8_fp8(b[nt], a1, acc[1][nt], 0, 0, 0);
        }
    }

    // ---- store: swapped operands -> lane holds row rl, 4 consecutive cols ----
    const int cl4 = (lane >> 4) * 4;
    const int colbase = wid * 64;
#pragma unroll
    for (int mt = 0; mt < 2; ++mt)
#pragma unroll
        for (int nt = 0; nt < 4; ++nt)
            *(f32x4*)(out + (row0 + mt * 16 + rl) * UNITS + colbase + nt * 16 + cl4) =
                acc[mt][nt];
}

// ---------------------------------------------------------------------------
// Fallback (ws too small): round-2 popcount path, known-correct.
// ---------------------------------------------------------------------------
__global__ __launch_bounds__(256) void pack_w_bits(const float* __restrict__ w,
                                                   u64* __restrict__ wp) {
    const int t = blockIdx.x;
    const int j = threadIdx.x;
    u64 s = 0, z = 0;
#pragma unroll
    for (int b = 0; b < 64; ++b) {
        const float v = w[(4 * b + t) * UNITS + j];
        s |= ((u64)(v < 0.0f)) << b;
        z |= ((u64)(v != 0.0f)) << b;
    }
    wp[j * 4 + t] = s;
    wp[1024 + j * 4 + t] = z;
}

__global__ __launch_bounds__(256) void bdense_pop(const float4* __restrict__ x4,
                                                  const u64* __restrict__ wp,
                                                  float4* __restrict__ out4) {
    const int tid = threadIdx.x;
    const int lane = tid & 63;
    const int wid = tid >> 6;
    const long row0 = (long)blockIdx.x * 32 + (long)wid * 8;

    u64 ws_[4][4], wz_[4][4];
#pragma unroll
    for (int i = 0; i < 4; ++i)
#pragma unroll
        for (int t = 0; t < 4; ++t) {
            ws_[i][t] = wp[(4 * lane + i) * 4 + t];
            wz_[i][t] = wp[1024 + (4 * lane + i) * 4 + t];
        }

#pragma unroll
    for (int r = 0; r < 8; ++r) {
        const float4 v = x4[(row0 + r) * (IN_FEATURES / 4) + lane];
        u64 rs[4], rz[4];
        rs[0] = __ballot(v.x < 0.0f); rz[0] = __ballot(v.x != 0.0f);
        rs[1] = __ballot(v.y < 0.0f); rz[1] = __ballot(v.y != 0.0f);
        rs[2] = __ballot(v.z < 0.0f); rz[2] = __ballot(v.z != 0.0f);
        rs[3] = __ballot(v.w < 0.0f); rz[3] = __ballot(v.w != 0.0f);
        float o[4];
#pragma unroll
        for (int i = 0; i < 4; ++i) {
            int nzc = 0, ngc = 0;
#pragma unroll
            for (int t = 0; t < 4; ++t) {
                const u64 nz = rz[t] & wz_[i][t];
                const u64 d = (rs[t] ^ ws_[i][t]) & nz;
                nzc += __popcll(nz);
                ngc += __popcll(d);
            }
            o[i] = (float)(nzc - 2 * ngc);
        }
        out4[(row0 + r) * (UNITS / 4) + lane] = make_float4(o[0], o[1], o[2], o[3]);
    }
}

extern "C" void kernel_launch(void* const* d_in, const int* in_sizes, int n_in,
                              void* d_out, int out_size, void* d_ws, size_t ws_size,
                              hipStream_t stream) {
    const float* x = (const float*)d_in[0];
    const float* w = (const float*)d_in[1];
    float* out = (float*)d_out;

    const int batch = in_sizes[0] / IN_FEATURES;  // 65536

    if (ws_size >= 65536) {  // fragB: 64 KB fp8 fragments
        u64* fragB = (u64*)d_ws;
        pack_w_frag8<<<16, 256, 0, stream>>>(w, fragB);
        bdense_fp8<<<batch / BM, 256, 0, stream>>>((const float4*)x, fragB, out);
    } else {
        u64* wp = (u64*)d_ws;  // 16 KB
        pack_w_bits<<<4, 256, 0, stream>>>(w, wp);
        bdense_pop<<<batch / 32, 256, 0, stream>>>((const float4*)x, wp, (float4*)out);
    }
}